// Round 8
// baseline (411.984 us; speedup 1.0000x reference)
//
#include <hip/hip_runtime.h>
#include <hip/hip_bf16.h>

constexpr int kD  = 1024;
constexpr int kH  = 16;
constexpr int kHD = 64;
constexpr int kS  = 64;
constexpr int kE  = 16;
constexpr int kB  = 32;
constexpr int kSB = kS * kB;   // 2048 (s,b) pairs

typedef __attribute__((ext_vector_type(8))) short bfvec8;   // 8 bf16 (4 VGPRs)
typedef __attribute__((ext_vector_type(4))) float fvec4;    // MFMA acc

struct __align__(8)  bf4  { __hip_bfloat16 v[4]; };
struct __align__(16) bf8v { __hip_bfloat16 v[8]; };

// ---------------- merged precompute: wmat+cvec / cb / Wobf (R4 proven, byte-identical) ----------------
__global__ __launch_bounds__(256) void k_pre2(const float* __restrict__ Wq_in,
                                              const float* __restrict__ query,
                                              const float* __restrict__ bq_in,
                                              const float* __restrict__ Wv_in,
                                              const float* __restrict__ bv_lin,
                                              const float* __restrict__ bv_in,
                                              const float* __restrict__ Wk_in,
                                              const float* __restrict__ bk_lin,
                                              const float* __restrict__ bk_in,
                                              const float* __restrict__ Wo,
                                              float* __restrict__ wmat,
                                              float* __restrict__ cvec,
                                              float* __restrict__ cb,
                                              __hip_bfloat16* __restrict__ Wobf) {
  int j = blockIdx.x, t = threadIdx.x;
  if (j < 64) {
    int h = j >> 2, chunk = j & 3;
    __shared__ float qs_s[64];
    __shared__ float kb2_s[64];
    int l = t & 63, w = t >> 6;
    int jj = w * 16 + (l >> 2);          // j-row within head (0..63)
    int part = l & 3;                    // 4 lanes split the 1024-dot
    {
      const float4* w4 = (const float4*)(Wq_in + (size_t)(h * 64 + jj) * kD);
      const float4* q4 = (const float4*)query;
      float acc = 0.f;
      #pragma unroll 4
      for (int i = 0; i < 64; i++) {
        float4 a = w4[part + 4 * i], b = q4[part + 4 * i];
        acc += a.x * b.x + a.y * b.y + a.z * b.z + a.w * b.w;
      }
      acc += __shfl_xor(acc, 1);
      acc += __shfl_xor(acc, 2);
      if (part == 0) qs_s[jj] = (acc + bq_in[h * 64 + jj]) * 0.125f;
    }
    if (chunk == 0) {
      const float4* w4 = (const float4*)(Wk_in + (size_t)(h * 64 + jj) * kD);
      const float4* q4 = (const float4*)bk_lin;
      float acc = 0.f;
      #pragma unroll 4
      for (int i = 0; i < 64; i++) {
        float4 a = w4[part + 4 * i], b = q4[part + 4 * i];
        acc += a.x * b.x + a.y * b.y + a.z * b.z + a.w * b.w;
      }
      acc += __shfl_xor(acc, 1);
      acc += __shfl_xor(acc, 2);
      if (part == 0) kb2_s[jj] = acc + bk_in[h * 64 + jj];
    }
    __syncthreads();
    int d = chunk * 256 + t;
    float acc = 0.f;
    #pragma unroll 8
    for (int jr = 0; jr < 64; jr++)
      acc = fmaf(qs_s[jr], Wk_in[(size_t)(h * 64 + jr) * kD + d], acc);
    wmat[(size_t)h * kD + d] = acc;
    if (chunk == 0 && t < 64) {
      float v = qs_s[t] * kb2_s[t];
      #pragma unroll
      for (int o = 32; o >= 1; o >>= 1) v += __shfl_xor(v, o);
      if (t == 0) cvec[h] = v;
    }
    return;
  }
  if (j < 1088) {                        // cb row
    int row = j - 64;
    const float4* w4 = (const float4*)(Wv_in + (size_t)row * kD);
    const float4* v4 = (const float4*)bv_lin;
    float4 a = w4[t], b = v4[t];
    float acc = a.x * b.x + a.y * b.y + a.z * b.z + a.w * b.w;
    #pragma unroll
    for (int o = 32; o >= 1; o >>= 1) acc += __shfl_xor(acc, o);
    __shared__ float red[4];
    if ((t & 63) == 0) red[t >> 6] = acc;
    __syncthreads();
    if (t == 0) cb[row] = red[0] + red[1] + red[2] + red[3] + bv_in[row];
    return;
  }
  // Wobf convert: one row per block, 4 elems/thread
  int i = (j - 1088) * kD + t * 4;
  float4 v = *(const float4*)(Wo + i);
  bf4 o;
  o.v[0] = __float2bfloat16(v.x); o.v[1] = __float2bfloat16(v.y);
  o.v[2] = __float2bfloat16(v.z); o.v[3] = __float2bfloat16(v.w);
  *(bf4*)(Wobf + i) = o;
}

// ---------------- fused attention (R0/R4 proven, byte-identical) ----------------
// NOTE R8: launched 3x (idempotent) purely to MEASURE its duration via the dur_us delta.

__global__ __launch_bounds__(256) void k_attn_eagg(const float* __restrict__ ent,
                                                   const unsigned char* __restrict__ pmask,
                                                   const __hip_bfloat16* __restrict__ Ubf,
                                                   const float* __restrict__ cvec,
                                                   __hip_bfloat16* __restrict__ eagg) {
  __shared__ __hip_bfloat16 ent_s[kE][kD + 8];      // pitch 1032
  __shared__ float sred[4][kE][kH + 1];             // per-wave partial S^T[e][h]
  __shared__ __hip_bfloat16 attn_b[kH][32];         // attn[h][e], cols 16..31 zero
  int sb = blockIdx.x;
  int s = sb >> 5, b = sb & 31;
  int t = threadIdx.x, l = t & 63, w = t >> 6;
  int quad = l >> 4, lane16 = l & 15;

  // ---- stage E x D entity tile -> LDS bf16 ----
  const float* src = ent + (size_t)(s * kE) * kB * kD + (size_t)b * kD;
  #pragma unroll
  for (int it = 0; it < 8; it++) {
    int i = t + it * 256;
    int e = i >> 7, f = (i & 127) * 8;
    const float4* pp = (const float4*)(src + (size_t)e * kB * kD + f);
    float4 v0 = pp[0], v1 = pp[1];
    bf8v pk;
    pk.v[0] = __float2bfloat16(v0.x); pk.v[1] = __float2bfloat16(v0.y);
    pk.v[2] = __float2bfloat16(v0.z); pk.v[3] = __float2bfloat16(v0.w);
    pk.v[4] = __float2bfloat16(v1.x); pk.v[5] = __float2bfloat16(v1.y);
    pk.v[6] = __float2bfloat16(v1.z); pk.v[7] = __float2bfloat16(v1.w);
    *(bf8v*)&ent_s[e][f] = pk;
  }
  __syncthreads();

  // ---- scores: S^T[e,h] = sum_d ent[e,d]*U[h,d]; K-split 256 per wave ----
  fvec4 sacc = {};
  #pragma unroll
  for (int ks = 0; ks < 8; ks++) {
    int k0 = w * 256 + ks * 32 + quad * 8;
    bfvec8 a = *(const bfvec8*)&ent_s[lane16][k0];
    bfvec8 bb = *(const bfvec8*)&Ubf[(size_t)lane16 * kD + k0];
    sacc = __builtin_amdgcn_mfma_f32_16x16x32_bf16(a, bb, sacc, 0, 0, 0);
  }
  #pragma unroll
  for (int i = 0; i < 4; i++) sred[w][quad * 4 + i][lane16] = sacc[i];
  __syncthreads();

  // ---- softmax over e (thread t: h = t>>4, e = t&15) ----
  {
    int h = t >> 4, e = t & 15;
    float sc = sred[0][e][h] + sred[1][e][h] + sred[2][e][h] + sred[3][e][h] + cvec[h];
    if (pmask[(size_t)(s * kE + e) * kB + b]) sc = -INFINITY;
    float m = sc;
    #pragma unroll
    for (int o = 8; o >= 1; o >>= 1) m = fmaxf(m, __shfl_xor(m, o, 16));
    float ex = __expf(sc - m);
    float sum = ex;
    #pragma unroll
    for (int o = 8; o >= 1; o >>= 1) sum += __shfl_xor(sum, o, 16);
    attn_b[h][e] = __float2bfloat16(ex / sum);
    attn_b[h][e + 16] = __float2bfloat16(0.f);
  }
  __syncthreads();

  // ---- eagg: D[m=d16][n=h] = sum_e ent^T[d,e]*attn[h,e]; 16 d-tiles per wave ----
  bfvec8 bfrag = *(const bfvec8*)&attn_b[lane16][quad * 8];
  __hip_bfloat16* dst = eagg + (size_t)sb * (kH * kD);
  for (int tt = 0; tt < 16; tt++) {
    int dme = (w * 16 + tt) * 16 + lane16;
    bfvec8 afrag = {};
    if (quad < 2) {
      #pragma unroll
      for (int j = 0; j < 8; j++)
        afrag[j] = *(const short*)&ent_s[quad * 8 + j][dme];
    }
    fvec4 acc = {};
    acc = __builtin_amdgcn_mfma_f32_16x16x32_bf16(afrag, bfrag, acc, 0, 0, 0);
    int d0 = (w * 16 + tt) * 16 + quad * 4;
    bf4 o;
    o.v[0] = __float2bfloat16(acc[0]); o.v[1] = __float2bfloat16(acc[1]);
    o.v[2] = __float2bfloat16(acc[2]); o.v[3] = __float2bfloat16(acc[3]);
    *(bf4*)&dst[(size_t)lane16 * kD + d0] = o;
  }
}

// ---------------- staging helpers ----------------

__device__ __forceinline__ void stage_row(const __hip_bfloat16* g, __hip_bfloat16* s) {
  *(bf8v*)s = *(const bf8v*)g;
}
__device__ __forceinline__ void stage_row(const float* g, __hip_bfloat16* s) {
  const float4* p = (const float4*)g;
  float4 v0 = p[0], v1 = p[1];
  bf8v pk;
  pk.v[0] = __float2bfloat16(v0.x); pk.v[1] = __float2bfloat16(v0.y);
  pk.v[2] = __float2bfloat16(v0.z); pk.v[3] = __float2bfloat16(v0.w);
  pk.v[4] = __float2bfloat16(v1.x); pk.v[5] = __float2bfloat16(v1.y);
  pk.v[6] = __float2bfloat16(v1.z); pk.v[7] = __float2bfloat16(v1.w);
  *(bf8v*)s = pk;
}

// ---------------- bf16 MFMA GEMM (NT), 64x64 tile (R0/R4 proven) ----------------
// MODE 0: f32 out. MODE 2: bf16 out. Bias added if non-null.

template <int MODE, typename TA, typename TB, typename TC>
__global__ __launch_bounds__(256) void k_gemm_mfma(
    const TA* __restrict__ Abase, int lda, long aBatch,
    const TB* __restrict__ Bbase, int ldb, long bBatch,
    TC* __restrict__ Cbase, int ldc, long cBatch,
    const float* __restrict__ bias, long biasBatch, int Ksz) {
  const TA* Ag = Abase + (size_t)blockIdx.z * aBatch;
  const TB* Bg = Bbase + (size_t)blockIdx.z * bBatch;
  TC* Cg = Cbase + (size_t)blockIdx.z * cBatch;
  const float* biasp = bias ? bias + (size_t)blockIdx.z * biasBatch : nullptr;
  const int m0 = blockIdx.x * 64, n0 = blockIdx.y * 64;
  __shared__ __hip_bfloat16 As[64][72];
  __shared__ __hip_bfloat16 Bs[64][72];
  const int t = threadIdx.x;
  const int l = t & 63, w = t >> 6;
  const int quad = l >> 4, col = l & 15;
  fvec4 acc[4] = {};
  for (int k0 = 0; k0 < Ksz; k0 += 64) {
    #pragma unroll
    for (int c = t; c < 512; c += 256) {
      int row = c >> 3, kq = (c & 7) * 8;
      stage_row(Ag + (size_t)(m0 + row) * lda + k0 + kq, &As[row][kq]);
      stage_row(Bg + (size_t)(n0 + row) * ldb + k0 + kq, &Bs[row][kq]);
    }
    __syncthreads();
    #pragma unroll
    for (int ks = 0; ks < 64; ks += 32) {
      bfvec8 a = *(const bfvec8*)&As[w * 16 + col][ks + quad * 8];
      #pragma unroll
      for (int nt = 0; nt < 4; nt++) {
        bfvec8 b = *(const bfvec8*)&Bs[nt * 16 + col][ks + quad * 8];
        acc[nt] = __builtin_amdgcn_mfma_f32_16x16x32_bf16(a, b, acc[nt], 0, 0, 0);
      }
    }
    __syncthreads();
  }
  #pragma unroll
  for (int nt = 0; nt < 4; nt++) {
    int n = n0 + nt * 16 + col;
    float bv = biasp ? biasp[n] : 0.f;
    #pragma unroll
    for (int i = 0; i < 4; i++) {
      int r = m0 + w * 16 + quad * 4 + i;
      float v = acc[nt][i] + bv;
      if constexpr (MODE == 0) ((float*)Cg)[(size_t)r * ldc + n] = v;
      else ((__hip_bfloat16*)Cg)[(size_t)r * ldc + n] = __float2bfloat16(v);
    }
  }
}

// ---------------- bf16 MFMA GEMM (NN, f32 in, bf16 out), 64x64 tile (R0/R4 proven) ----------------

__global__ __launch_bounds__(256) void k_gemm_nn(
    const float* __restrict__ A0, const float* __restrict__ B0,
    __hip_bfloat16* __restrict__ C0,
    const float* __restrict__ A1, const float* __restrict__ B1,
    __hip_bfloat16* __restrict__ C1, int Ksz) {
  const bool isU = (blockIdx.x == 16);
  const float* Ag = isU ? A1 : A0;
  const float* Bg = isU ? B1 : B0;
  __hip_bfloat16* Cg = isU ? C1 : C0;
  const int m0 = isU ? 0 : blockIdx.x * 64, n0 = blockIdx.y * 64;
  __shared__ __hip_bfloat16 As[64][72];
  __shared__ __hip_bfloat16 Bs[64][72];
  const int t = threadIdx.x;
  const int l = t & 63, w = t >> 6;
  const int quad = l >> 4, col = l & 15;
  fvec4 acc[4] = {};
  for (int k0 = 0; k0 < Ksz; k0 += 64) {
    #pragma unroll
    for (int c = t; c < 512; c += 256) {
      int row = c >> 3, kq = (c & 7) * 8;
      stage_row(Ag + (size_t)(m0 + row) * kD + k0 + kq, &As[row][kq]);
      const float4* pb = (const float4*)(Bg + (size_t)(k0 + row) * kD + n0 + kq);
      float4 b0 = pb[0], b1 = pb[1];
      Bs[kq + 0][row] = __float2bfloat16(b0.x);
      Bs[kq + 1][row] = __float2bfloat16(b0.y);
      Bs[kq + 2][row] = __float2bfloat16(b0.z);
      Bs[kq + 3][row] = __float2bfloat16(b0.w);
      Bs[kq + 4][row] = __float2bfloat16(b1.x);
      Bs[kq + 5][row] = __float2bfloat16(b1.y);
      Bs[kq + 6][row] = __float2bfloat16(b1.z);
      Bs[kq + 7][row] = __float2bfloat16(b1.w);
    }
    __syncthreads();
    #pragma unroll
    for (int ks = 0; ks < 64; ks += 32) {
      bfvec8 a = *(const bfvec8*)&As[w * 16 + col][ks + quad * 8];
      #pragma unroll
      for (int nt = 0; nt < 4; nt++) {
        bfvec8 b = *(const bfvec8*)&Bs[nt * 16 + col][ks + quad * 8];
        acc[nt] = __builtin_amdgcn_mfma_f32_16x16x32_bf16(a, b, acc[nt], 0, 0, 0);
      }
    }
    __syncthreads();
  }
  #pragma unroll
  for (int nt = 0; nt < 4; nt++) {
    int n = n0 + nt * 16 + col;
    #pragma unroll
    for (int i = 0; i < 4; i++) {
      int r = m0 + w * 16 + quad * 4 + i;
      Cg[(size_t)r * kD + n] = __float2bfloat16(acc[nt][i]);
    }
  }
}

extern "C" void kernel_launch(void* const* d_in, const int* in_sizes, int n_in,
                              void* d_out, int out_size, void* d_ws, size_t ws_size,
                              hipStream_t stream) {
  const float* ent            = (const float*)d_in[0];
  const unsigned char* pmask  = (const unsigned char*)d_in[1];
  const float* query          = (const float*)d_in[3];
  const float* Wk_lin         = (const float*)d_in[4];
  const float* bk_lin         = (const float*)d_in[5];
  const float* Wv_lin         = (const float*)d_in[6];
  const float* bv_lin         = (const float*)d_in[7];
  const float* Wq_in          = (const float*)d_in[8];
  const float* bq_in          = (const float*)d_in[9];
  const float* Wk_in          = (const float*)d_in[10];
  const float* bk_in          = (const float*)d_in[11];
  const float* Wv_in          = (const float*)d_in[12];
  const float* bv_in          = (const float*)d_in[13];
  const float* Wo             = (const float*)d_in[14];
  const float* bo             = (const float*)d_in[15];
  float* out = (float*)d_out;

  float* p = (float*)d_ws;
  float* wmat = p; p += 64 * kD;         // w[h,d] rows 0..15 valid
  float* cvec = p; p += 256;             // c[h]
  float* cb   = p; p += kD;              // Wv_in@bv_lin + bv_in
  __hip_bfloat16* bp = (__hip_bfloat16*)p;
  __hip_bfloat16* Ubf  = bp; bp += (size_t)64 * kD;    // U[h][d] bf16 (rows 0..15 valid)
  __hip_bfloat16* Mmat = bp; bp += (size_t)kD * kD;    // Wv_in @ Wv_lin bf16
  __hip_bfloat16* Wobf = bp; bp += (size_t)kD * kD;    // Wo bf16
  __hip_bfloat16* ctx2 = bp; bp += (size_t)kSB * kD;   // ctx bf16 [SB, D]
  __hip_bfloat16* eagg = bp;                           // [SB, H, D] bf16

  // ---- measurement build: R4 + attn launched 3x (idempotent) ----
  k_pre2<<<2112, 256, 0, stream>>>(Wq_in, query, bq_in, Wv_in, bv_lin, bv_in,
                                   Wk_in, bk_lin, bk_in, Wo,
                                   wmat, cvec, cb, Wobf);
  k_gemm_nn<<<dim3(17, 16, 1), 256, 0, stream>>>(Wv_in, Wv_lin, Mmat,
                                                 wmat, Wk_lin, Ubf, kD);
  k_attn_eagg<<<kSB, 256, 0, stream>>>(ent, pmask, Ubf, cvec, eagg);
  k_attn_eagg<<<kSB, 256, 0, stream>>>(ent, pmask, Ubf, cvec, eagg);   // dup #1 (measure)
  k_attn_eagg<<<kSB, 256, 0, stream>>>(ent, pmask, Ubf, cvec, eagg);   // dup #2 (measure)
  k_gemm_mfma<2, __hip_bfloat16, __hip_bfloat16, __hip_bfloat16>
      <<<dim3(kSB / 64, 1, kH), 256, 0, stream>>>(
      eagg, kH * kD, (long)kD, Mmat, kD, (long)(kHD * kD),
      ctx2, kD, (long)kHD, cb, (long)kHD, kD);
  k_gemm_mfma<0, __hip_bfloat16, __hip_bfloat16, float>
      <<<dim3(kSB / 64, kD / 64, 1), 256, 0, stream>>>(
      ctx2, kD, 0L, Wobf, kD, 0L, out, kD, 0L, bo, 0L, kD);
}

// Round 9
// 330.388 us; speedup vs baseline: 1.2470x; 1.2470x over previous
//
#include <hip/hip_runtime.h>
#include <hip/hip_bf16.h>

constexpr int kD  = 1024;
constexpr int kH  = 16;
constexpr int kHD = 64;
constexpr int kS  = 64;
constexpr int kE  = 16;
constexpr int kB  = 32;
constexpr int kSB = kS * kB;   // 2048 (s,b) pairs

typedef __attribute__((ext_vector_type(8))) short bfvec8;   // 8 bf16 (4 VGPRs)
typedef __attribute__((ext_vector_type(4))) float fvec4;    // MFMA acc

struct __align__(8)  bf4  { __hip_bfloat16 v[4]; };
struct __align__(16) bf8v { __hip_bfloat16 v[8]; };

// ---------------- merged precompute: wmat+cvec / cb / Wobf (R4 proven, byte-identical) ----------------
__global__ __launch_bounds__(256) void k_pre2(const float* __restrict__ Wq_in,
                                              const float* __restrict__ query,
                                              const float* __restrict__ bq_in,
                                              const float* __restrict__ Wv_in,
                                              const float* __restrict__ bv_lin,
                                              const float* __restrict__ bv_in,
                                              const float* __restrict__ Wk_in,
                                              const float* __restrict__ bk_lin,
                                              const float* __restrict__ bk_in,
                                              const float* __restrict__ Wo,
                                              float* __restrict__ wmat,
                                              float* __restrict__ cvec,
                                              float* __restrict__ cb,
                                              __hip_bfloat16* __restrict__ Wobf) {
  int j = blockIdx.x, t = threadIdx.x;
  if (j < 64) {
    int h = j >> 2, chunk = j & 3;
    __shared__ float qs_s[64];
    __shared__ float kb2_s[64];
    int l = t & 63, w = t >> 6;
    int jj = w * 16 + (l >> 2);          // j-row within head (0..63)
    int part = l & 3;                    // 4 lanes split the 1024-dot
    {
      const float4* w4 = (const float4*)(Wq_in + (size_t)(h * 64 + jj) * kD);
      const float4* q4 = (const float4*)query;
      float acc = 0.f;
      #pragma unroll 4
      for (int i = 0; i < 64; i++) {
        float4 a = w4[part + 4 * i], b = q4[part + 4 * i];
        acc += a.x * b.x + a.y * b.y + a.z * b.z + a.w * b.w;
      }
      acc += __shfl_xor(acc, 1);
      acc += __shfl_xor(acc, 2);
      if (part == 0) qs_s[jj] = (acc + bq_in[h * 64 + jj]) * 0.125f;
    }
    if (chunk == 0) {
      const float4* w4 = (const float4*)(Wk_in + (size_t)(h * 64 + jj) * kD);
      const float4* q4 = (const float4*)bk_lin;
      float acc = 0.f;
      #pragma unroll 4
      for (int i = 0; i < 64; i++) {
        float4 a = w4[part + 4 * i], b = q4[part + 4 * i];
        acc += a.x * b.x + a.y * b.y + a.z * b.z + a.w * b.w;
      }
      acc += __shfl_xor(acc, 1);
      acc += __shfl_xor(acc, 2);
      if (part == 0) kb2_s[jj] = acc + bk_in[h * 64 + jj];
    }
    __syncthreads();
    int d = chunk * 256 + t;
    float acc = 0.f;
    #pragma unroll 8
    for (int jr = 0; jr < 64; jr++)
      acc = fmaf(qs_s[jr], Wk_in[(size_t)(h * 64 + jr) * kD + d], acc);
    wmat[(size_t)h * kD + d] = acc;
    if (chunk == 0 && t < 64) {
      float v = qs_s[t] * kb2_s[t];
      #pragma unroll
      for (int o = 32; o >= 1; o >>= 1) v += __shfl_xor(v, o);
      if (t == 0) cvec[h] = v;
    }
    return;
  }
  if (j < 1088) {                        // cb row
    int row = j - 64;
    const float4* w4 = (const float4*)(Wv_in + (size_t)row * kD);
    const float4* v4 = (const float4*)bv_lin;
    float4 a = w4[t], b = v4[t];
    float acc = a.x * b.x + a.y * b.y + a.z * b.z + a.w * b.w;
    #pragma unroll
    for (int o = 32; o >= 1; o >>= 1) acc += __shfl_xor(acc, o);
    __shared__ float red[4];
    if ((t & 63) == 0) red[t >> 6] = acc;
    __syncthreads();
    if (t == 0) cb[row] = red[0] + red[1] + red[2] + red[3] + bv_in[row];
    return;
  }
  // Wobf convert: one row per block, 4 elems/thread
  int i = (j - 1088) * kD + t * 4;
  float4 v = *(const float4*)(Wo + i);
  bf4 o;
  o.v[0] = __float2bfloat16(v.x); o.v[1] = __float2bfloat16(v.y);
  o.v[2] = __float2bfloat16(v.z); o.v[3] = __float2bfloat16(v.w);
  *(bf4*)(Wobf + i) = o;
}

// ---------------- fused attention (R0/R4 proven, byte-identical; at roofline per R8) ----------------

__global__ __launch_bounds__(256) void k_attn_eagg(const float* __restrict__ ent,
                                                   const unsigned char* __restrict__ pmask,
                                                   const __hip_bfloat16* __restrict__ Ubf,
                                                   const float* __restrict__ cvec,
                                                   __hip_bfloat16* __restrict__ eagg) {
  __shared__ __hip_bfloat16 ent_s[kE][kD + 8];      // pitch 1032
  __shared__ float sred[4][kE][kH + 1];             // per-wave partial S^T[e][h]
  __shared__ __hip_bfloat16 attn_b[kH][32];         // attn[h][e], cols 16..31 zero
  int sb = blockIdx.x;
  int s = sb >> 5, b = sb & 31;
  int t = threadIdx.x, l = t & 63, w = t >> 6;
  int quad = l >> 4, lane16 = l & 15;

  // ---- stage E x D entity tile -> LDS bf16 ----
  const float* src = ent + (size_t)(s * kE) * kB * kD + (size_t)b * kD;
  #pragma unroll
  for (int it = 0; it < 8; it++) {
    int i = t + it * 256;
    int e = i >> 7, f = (i & 127) * 8;
    const float4* pp = (const float4*)(src + (size_t)e * kB * kD + f);
    float4 v0 = pp[0], v1 = pp[1];
    bf8v pk;
    pk.v[0] = __float2bfloat16(v0.x); pk.v[1] = __float2bfloat16(v0.y);
    pk.v[2] = __float2bfloat16(v0.z); pk.v[3] = __float2bfloat16(v0.w);
    pk.v[4] = __float2bfloat16(v1.x); pk.v[5] = __float2bfloat16(v1.y);
    pk.v[6] = __float2bfloat16(v1.z); pk.v[7] = __float2bfloat16(v1.w);
    *(bf8v*)&ent_s[e][f] = pk;
  }
  __syncthreads();

  // ---- scores: S^T[e,h] = sum_d ent[e,d]*U[h,d]; K-split 256 per wave ----
  fvec4 sacc = {};
  #pragma unroll
  for (int ks = 0; ks < 8; ks++) {
    int k0 = w * 256 + ks * 32 + quad * 8;
    bfvec8 a = *(const bfvec8*)&ent_s[lane16][k0];
    bfvec8 bb = *(const bfvec8*)&Ubf[(size_t)lane16 * kD + k0];
    sacc = __builtin_amdgcn_mfma_f32_16x16x32_bf16(a, bb, sacc, 0, 0, 0);
  }
  #pragma unroll
  for (int i = 0; i < 4; i++) sred[w][quad * 4 + i][lane16] = sacc[i];
  __syncthreads();

  // ---- softmax over e (thread t: h = t>>4, e = t&15) ----
  {
    int h = t >> 4, e = t & 15;
    float sc = sred[0][e][h] + sred[1][e][h] + sred[2][e][h] + sred[3][e][h] + cvec[h];
    if (pmask[(size_t)(s * kE + e) * kB + b]) sc = -INFINITY;
    float m = sc;
    #pragma unroll
    for (int o = 8; o >= 1; o >>= 1) m = fmaxf(m, __shfl_xor(m, o, 16));
    float ex = __expf(sc - m);
    float sum = ex;
    #pragma unroll
    for (int o = 8; o >= 1; o >>= 1) sum += __shfl_xor(sum, o, 16);
    attn_b[h][e] = __float2bfloat16(ex / sum);
    attn_b[h][e + 16] = __float2bfloat16(0.f);
  }
  __syncthreads();

  // ---- eagg: D[m=d16][n=h] = sum_e ent^T[d,e]*attn[h,e]; 16 d-tiles per wave ----
  bfvec8 bfrag = *(const bfvec8*)&attn_b[lane16][quad * 8];
  __hip_bfloat16* dst = eagg + (size_t)sb * (kH * kD);
  for (int tt = 0; tt < 16; tt++) {
    int dme = (w * 16 + tt) * 16 + lane16;
    bfvec8 afrag = {};
    if (quad < 2) {
      #pragma unroll
      for (int j = 0; j < 8; j++)
        afrag[j] = *(const short*)&ent_s[quad * 8 + j][dme];
    }
    fvec4 acc = {};
    acc = __builtin_amdgcn_mfma_f32_16x16x32_bf16(afrag, bfrag, acc, 0, 0, 0);
    int d0 = (w * 16 + tt) * 16 + quad * 4;
    bf4 o;
    o.v[0] = __float2bfloat16(acc[0]); o.v[1] = __float2bfloat16(acc[1]);
    o.v[2] = __float2bfloat16(acc[2]); o.v[3] = __float2bfloat16(acc[3]);
    *(bf4*)&dst[(size_t)lane16 * kD + d0] = o;
  }
}

// ---------------- staging helpers ----------------

__device__ __forceinline__ void stage_row(const __hip_bfloat16* g, __hip_bfloat16* s) {
  *(bf8v*)s = *(const bf8v*)g;
}
__device__ __forceinline__ void stage_row(const float* g, __hip_bfloat16* s) {
  const float4* p = (const float4*)g;
  float4 v0 = p[0], v1 = p[1];
  bf8v pk;
  pk.v[0] = __float2bfloat16(v0.x); pk.v[1] = __float2bfloat16(v0.y);
  pk.v[2] = __float2bfloat16(v0.z); pk.v[3] = __float2bfloat16(v0.w);
  pk.v[4] = __float2bfloat16(v1.x); pk.v[5] = __float2bfloat16(v1.y);
  pk.v[6] = __float2bfloat16(v1.z); pk.v[7] = __float2bfloat16(v1.w);
  *(bf8v*)s = pk;
}

// ---------------- global_load_lds 16B (direct HBM->LDS, no VGPR roundtrip) ----------------
// LDS dest is WAVE-UNIFORM base; HW adds lane*16 (m104). Source addr is per-lane.
__device__ __forceinline__ void gload16(const __hip_bfloat16* g, __hip_bfloat16* l) {
  __builtin_amdgcn_global_load_lds(
      (const __attribute__((address_space(1))) unsigned int*)g,
      (__attribute__((address_space(3))) unsigned int*)l, 16, 0, 0);
}

// ---------------- bf16 MFMA GEMM (NT), 64x64 tile, global_load_lds staging ----------------
// LDS tile [64 rows][8 slots of 8 bf16]; logical slot c stored at (c ^ (row&7))
// via PRE-SWIZZLED global source + linear LDS dest (rule #21); reads apply same XOR.
// Read conflict: 2-way (free). Fragment contents bit-identical to R4 path.
// MODE 0: f32 out. MODE 2: bf16 out. Bias added if non-null.

template <int MODE, typename TC>
__global__ __launch_bounds__(256) void k_gemm_mfma(
    const __hip_bfloat16* __restrict__ Abase, int lda, long aBatch,
    const __hip_bfloat16* __restrict__ Bbase, int ldb, long bBatch,
    TC* __restrict__ Cbase, int ldc, long cBatch,
    const float* __restrict__ bias, long biasBatch, int Ksz) {
  const __hip_bfloat16* Ag = Abase + (size_t)blockIdx.z * aBatch;
  const __hip_bfloat16* Bg = Bbase + (size_t)blockIdx.z * bBatch;
  TC* Cg = Cbase + (size_t)blockIdx.z * cBatch;
  const float* biasp = bias ? bias + (size_t)blockIdx.z * biasBatch : nullptr;
  const int m0 = blockIdx.x * 64, n0 = blockIdx.y * 64;
  __shared__ __align__(16) __hip_bfloat16 As[64 * 64];
  __shared__ __align__(16) __hip_bfloat16 Bs[64 * 64];
  const int t = threadIdx.x;
  const int l = t & 63, w = t >> 6;
  const int quad = l >> 4, col = l & 15;
  fvec4 acc[4] = {};
  for (int k0 = 0; k0 < Ksz; k0 += 64) {
    #pragma unroll
    for (int i = 0; i < 2; i++) {
      int row = w * 16 + i * 8 + (l >> 3);                 // per-lane row
      int c = (l & 7) ^ (row & 7);                         // pre-swizzled k-slot
      __hip_bfloat16* ldst = &As[w * 1024 + i * 512];      // wave-uniform LDS base
      gload16(Ag + (size_t)(m0 + row) * lda + k0 + c * 8, ldst);
      gload16(Bg + (size_t)(n0 + row) * ldb + k0 + c * 8, &Bs[w * 1024 + i * 512]);
    }
    __syncthreads();   // compiler drains vmcnt before barrier -> LDS tiles ready
    #pragma unroll
    for (int ks = 0; ks < 64; ks += 32) {
      int arow = w * 16 + col;
      int kb = (ks >> 3) + quad;
      bfvec8 a = *(const bfvec8*)&As[arow * 64 + ((kb ^ (arow & 7)) << 3)];
      #pragma unroll
      for (int nt = 0; nt < 4; nt++) {
        int brow = nt * 16 + col;
        bfvec8 b = *(const bfvec8*)&Bs[brow * 64 + ((kb ^ (brow & 7)) << 3)];
        acc[nt] = __builtin_amdgcn_mfma_f32_16x16x32_bf16(a, b, acc[nt], 0, 0, 0);
      }
    }
    __syncthreads();
  }
  #pragma unroll
  for (int nt = 0; nt < 4; nt++) {
    int n = n0 + nt * 16 + col;
    float bv = biasp ? biasp[n] : 0.f;
    #pragma unroll
    for (int i = 0; i < 4; i++) {
      int r = m0 + w * 16 + quad * 4 + i;
      float v = acc[nt][i] + bv;
      if constexpr (MODE == 0) ((float*)Cg)[(size_t)r * ldc + n] = v;
      else ((__hip_bfloat16*)Cg)[(size_t)r * ldc + n] = __float2bfloat16(v);
    }
  }
}

// ---------------- bf16 MFMA GEMM (NN, f32 in, bf16 out), 64x64 tile (R4 proven, byte-identical) ----------------

__global__ __launch_bounds__(256) void k_gemm_nn(
    const float* __restrict__ A0, const float* __restrict__ B0,
    __hip_bfloat16* __restrict__ C0,
    const float* __restrict__ A1, const float* __restrict__ B1,
    __hip_bfloat16* __restrict__ C1, int Ksz) {
  const bool isU = (blockIdx.x == 16);
  const float* Ag = isU ? A1 : A0;
  const float* Bg = isU ? B1 : B0;
  __hip_bfloat16* Cg = isU ? C1 : C0;
  const int m0 = isU ? 0 : blockIdx.x * 64, n0 = blockIdx.y * 64;
  __shared__ __hip_bfloat16 As[64][72];
  __shared__ __hip_bfloat16 Bs[64][72];
  const int t = threadIdx.x;
  const int l = t & 63, w = t >> 6;
  const int quad = l >> 4, col = l & 15;
  fvec4 acc[4] = {};
  for (int k0 = 0; k0 < Ksz; k0 += 64) {
    #pragma unroll
    for (int c = t; c < 512; c += 256) {
      int row = c >> 3, kq = (c & 7) * 8;
      stage_row(Ag + (size_t)(m0 + row) * kD + k0 + kq, &As[row][kq]);
      const float4* pb = (const float4*)(Bg + (size_t)(k0 + row) * kD + n0 + kq);
      float4 b0 = pb[0], b1 = pb[1];
      Bs[kq + 0][row] = __float2bfloat16(b0.x);
      Bs[kq + 1][row] = __float2bfloat16(b0.y);
      Bs[kq + 2][row] = __float2bfloat16(b0.z);
      Bs[kq + 3][row] = __float2bfloat16(b0.w);
      Bs[kq + 4][row] = __float2bfloat16(b1.x);
      Bs[kq + 5][row] = __float2bfloat16(b1.y);
      Bs[kq + 6][row] = __float2bfloat16(b1.z);
      Bs[kq + 7][row] = __float2bfloat16(b1.w);
    }
    __syncthreads();
    #pragma unroll
    for (int ks = 0; ks < 64; ks += 32) {
      bfvec8 a = *(const bfvec8*)&As[w * 16 + col][ks + quad * 8];
      #pragma unroll
      for (int nt = 0; nt < 4; nt++) {
        bfvec8 b = *(const bfvec8*)&Bs[nt * 16 + col][ks + quad * 8];
        acc[nt] = __builtin_amdgcn_mfma_f32_16x16x32_bf16(a, b, acc[nt], 0, 0, 0);
      }
    }
    __syncthreads();
  }
  #pragma unroll
  for (int nt = 0; nt < 4; nt++) {
    int n = n0 + nt * 16 + col;
    #pragma unroll
    for (int i = 0; i < 4; i++) {
      int r = m0 + w * 16 + quad * 4 + i;
      Cg[(size_t)r * kD + n] = __float2bfloat16(acc[nt][i]);
    }
  }
}

extern "C" void kernel_launch(void* const* d_in, const int* in_sizes, int n_in,
                              void* d_out, int out_size, void* d_ws, size_t ws_size,
                              hipStream_t stream) {
  const float* ent            = (const float*)d_in[0];
  const unsigned char* pmask  = (const unsigned char*)d_in[1];
  const float* query          = (const float*)d_in[3];
  const float* Wk_lin         = (const float*)d_in[4];
  const float* bk_lin         = (const float*)d_in[5];
  const float* Wv_lin         = (const float*)d_in[6];
  const float* bv_lin         = (const float*)d_in[7];
  const float* Wq_in          = (const float*)d_in[8];
  const float* bq_in          = (const float*)d_in[9];
  const float* Wk_in          = (const float*)d_in[10];
  const float* bk_in          = (const float*)d_in[11];
  const float* Wv_in          = (const float*)d_in[12];
  const float* bv_in          = (const float*)d_in[13];
  const float* Wo             = (const float*)d_in[14];
  const float* bo             = (const float*)d_in[15];
  float* out = (float*)d_out;

  float* p = (float*)d_ws;
  float* wmat = p; p += 64 * kD;         // w[h,d] rows 0..15 valid
  float* cvec = p; p += 256;             // c[h]
  float* cb   = p; p += kD;              // Wv_in@bv_lin + bv_in
  __hip_bfloat16* bp = (__hip_bfloat16*)p;
  __hip_bfloat16* Ubf  = bp; bp += (size_t)64 * kD;    // U[h][d] bf16 (rows 0..15 valid)
  __hip_bfloat16* Mmat = bp; bp += (size_t)kD * kD;    // Wv_in @ Wv_lin bf16
  __hip_bfloat16* Wobf = bp; bp += (size_t)kD * kD;    // Wo bf16
  __hip_bfloat16* ctx2 = bp; bp += (size_t)kSB * kD;   // ctx bf16 [SB, D]
  __hip_bfloat16* eagg = bp;                           // [SB, H, D] bf16

  // ---- 5 dispatches total ----
  k_pre2<<<2112, 256, 0, stream>>>(Wq_in, query, bq_in, Wv_in, bv_lin, bv_in,
                                   Wk_in, bk_lin, bk_in, Wo,
                                   wmat, cvec, cb, Wobf);
  k_gemm_nn<<<dim3(17, 16, 1), 256, 0, stream>>>(Wv_in, Wv_lin, Mmat,
                                                 wmat, Wk_lin, Ubf, kD);
  k_attn_eagg<<<kSB, 256, 0, stream>>>(ent, pmask, Ubf, cvec, eagg);
  // ctx[sb, h*64+n] = eagg[sb,h,:] @ M_h^T + cb  (batched over h = z), bf16 out
  k_gemm_mfma<2, __hip_bfloat16><<<dim3(kSB / 64, 1, kH), 256, 0, stream>>>(
      eagg, kH * kD, (long)kD, Mmat, kD, (long)(kHD * kD),
      ctx2, kD, (long)kHD, cb, (long)kHD, kD);
  // out = ctx @ Wo^T + bo
  k_gemm_mfma<0, float><<<dim3(kSB / 64, kD / 64, 1), 256, 0, stream>>>(
      ctx2, kD, 0L, Wobf, kD, 0L, out, kD, 0L, bo, 0L, kD);
}